// Round 1
// 2591.571 us; speedup vs baseline: 1.0558x; 1.0558x over previous
//
#include <hip/hip_runtime.h>

// Problem constants (from reference)
#define EDIM 256
#define SLEN 64
#define TLEN 512
#define NT 1024
#define NWAVES 16

// ---- pre-pass: transpose+pack  out[c*out_stride + out_off + r] = in[r*C + c] ----
__global__ __launch_bounds__(256) void transpose_pack_kernel(
    const float* __restrict__ in, float* __restrict__ out, int R, int C,
    int out_stride, int out_off)
{
    __shared__ float tile[64][65];
    const int r0 = blockIdx.y * 64;
    const int c0 = blockIdx.x * 64;
#pragma unroll
    for (int i = threadIdx.x; i < 64 * 64; i += 256) {
        int r = i >> 6, c = i & 63;
        tile[r][c] = in[(size_t)(r0 + r) * C + (c0 + c)];
    }
    __syncthreads();
#pragma unroll
    for (int i = threadIdx.x; i < 64 * 64; i += 256) {
        int c = i >> 6, r = i & 63;
        out[(size_t)(c0 + c) * out_stride + out_off + (r0 + r)] = tile[r][c];
    }
}

__global__ __launch_bounds__(NT) void gru_decoder_kernel(
    const float* __restrict__ signal,       // [B,T,E] fp32
    const float* __restrict__ bases,        // [B,S,E]
    const int* __restrict__ mask,           // [B,T] int32 (nonzero = masked)
    const float* __restrict__ WcombT,       // [256k][1024r]: r<256 -> Ww[r][k]; r>=256 -> whh[r-256][k]
    const float* __restrict__ Wb,           // [E]
    const float* __restrict__ lng,          // [2E]
    const float* __restrict__ lnb,          // [2E]
    const float* __restrict__ wihT,         // [512k][768r]: wihT[k][j] = wih[j][k]
    const float* __restrict__ bih,          // [3E]
    const float* __restrict__ bhh,          // [3E]
    const float* __restrict__ hinit,        // [E]
    float* __restrict__ out)                // [B,S,E]
{
    const int b    = blockIdx.x;
    const int tid  = threadIdx.x;
    const int lane = tid & 63;
    const int wv   = tid >> 6;

    __shared__ float h_s[EDIM];
    __shared__ float v_s[EDIM];
    __shared__ float vghp[4 * 1024];     // AGH partials: rows 0..255 -> v, 256..1023 -> gh (lives until phase E)
    __shared__ float pool[8 * 768];      // 24KB: ctxp[16][256] (BC) aliased with gxp[8][768] (GX)
    __shared__ float inp_s[2 * EDIM];
    __shared__ float inpn_s[2 * EDIM];
    __shared__ float embias_s[TLEN];     // step-invariant mask bias
    __shared__ float mw_s[NWAVES], lw_s[NWAVES], ews_s[NWAVES];
    __shared__ float scr2[2 * NWAVES];

    float* ctxp = pool;                  // 16*256 floats
    float* gxp  = pool;                  // 8*768 floats (disjoint lifetime vs ctxp)

    const float* sigb  = signal + (size_t)b * TLEN * EDIM;
    const int*   maskb = mask + (size_t)b * TLEN;

    if (tid < EDIM) h_s[tid] = hinit[tid];
    if (tid < TLEN) embias_s[tid] = maskb[tid] ? -1e30f : 0.0f;
    __syncthreads();

    for (int s = 0; s < SLEN; ++s) {
        // ---- Phase AGH: [v; gh] = [Ww; whh] @ h. 1024 workers, 4-way k-split (64 k),
        //      worker owns 4 rows of the stacked 1024-row matrix (float4 loads, 1KB/wave).
        {
            const int q  = tid >> 8;            // 0..3 (wave-uniform), k in [q*64, q*64+64)
            const int r4 = (tid & 255) * 4;     // 0..1020
            const float* base = WcombT + (size_t)(q * 64) * 1024 + r4;
            const float* xk = &h_s[q * 64];
            float a0 = 0.f, a1 = 0.f, a2 = 0.f, a3 = 0.f;
#pragma unroll 8
            for (int k = 0; k < 64; ++k) {
                float4 w4 = *reinterpret_cast<const float4*>(base + (size_t)k * 1024);
                float x = xk[k];
                a0 += w4.x * x; a1 += w4.y * x; a2 += w4.z * x; a3 += w4.w * x;
            }
            float4 acc; acc.x = a0; acc.y = a1; acc.z = a2; acc.w = a3;
            *reinterpret_cast<float4*>(&vghp[q * 1024 + r4]) = acc;
        }
        __syncthreads();                        // (1) vghp ready

        float xreg = 0.f;                       // bases element, prefetched here, used at inp build
        if (tid < EDIM) {
            float v = Wb[tid];
#pragma unroll
            for (int q = 0; q < 4; ++q) v += vghp[q * 1024 + tid];
            v_s[tid] = v;
        } else if (tid < 2 * EDIM) {
            xreg = bases[((size_t)b * SLEN + s) * EDIM + (tid - EDIM)];
        }
        __syncthreads();                        // (2) v_s ready

        // ---- Fused attention (flash-style): e[t] = v.sig[t]; online softmax; ctx += p*sig[t].
        //      Wave owns 32 consecutive t; lane owns e-slice [lane*4, lane*4+4). Signal read ONCE.
        {
            float4 v4 = *reinterpret_cast<const float4*>(&v_s[lane * 4]);
            float m = -3e38f, l = 0.f;
            float c0 = 0.f, c1 = 0.f, c2 = 0.f, c3 = 0.f;
            const int t0 = wv * 32;
#pragma unroll 4
            for (int i = 0; i < 32; i += 2) {
                const int ta = t0 + i, tb = ta + 1;
                float4 A = *reinterpret_cast<const float4*>(sigb + (size_t)ta * EDIM + lane * 4);
                float4 B = *reinterpret_cast<const float4*>(sigb + (size_t)tb * EDIM + lane * 4);
                float da = A.x * v4.x + A.y * v4.y + A.z * v4.z + A.w * v4.w;
                float db = B.x * v4.x + B.y * v4.y + B.z * v4.z + B.w * v4.w;
#pragma unroll
                for (int mk = 32; mk > 0; mk >>= 1) {
                    da += __shfl_xor(da, mk, 64);
                    db += __shfl_xor(db, mk, 64);
                }
                float ea = da + embias_s[ta];       // masked -> ~-1e30
                float eb = db + embias_s[tb];
                float mn = fmaxf(m, fmaxf(ea, eb));
                float sc = __expf(m - mn);          // first iter: exp(-inf)=0
                float pa = __expf(ea - mn);
                float pb = __expf(eb - mn);
                l  = l  * sc + pa + pb;
                c0 = c0 * sc + pa * A.x + pb * B.x;
                c1 = c1 * sc + pa * A.y + pb * B.y;
                c2 = c2 * sc + pa * A.z + pb * B.z;
                c3 = c3 * sc + pa * A.w + pb * B.w;
                m = mn;
            }
            if (lane == 0) { mw_s[wv] = m; lw_s[wv] = l; }
            float4 cc; cc.x = c0; cc.y = c1; cc.z = c2; cc.w = c3;
            *reinterpret_cast<float4*>(&ctxp[wv * EDIM + lane * 4]) = cc;
            // note: fully-masked waves produce bogus (l,ctx) but m=-1e30 -> ews=0 kills them
        }
        __syncthreads();                        // (3) ctxp/mw/lw ready

        if (tid < NWAVES) {
            float M = mw_s[0];
#pragma unroll
            for (int w = 1; w < NWAVES; ++w) M = fmaxf(M, mw_s[w]);
            ews_s[tid] = __expf(mw_s[tid] - M);
        }
        __syncthreads();                        // (4) ews ready

        // ---- build inp = concat(x, ctx/L) ----
        if (tid < EDIM) {
            float L = 0.f, c = 0.f;
#pragma unroll
            for (int w = 0; w < NWAVES; ++w) {
                float ew = ews_s[w];
                L += lw_s[w] * ew;
                c += ctxp[w * EDIM + tid] * ew;
            }
            inp_s[EDIM + tid] = c / L;
        } else if (tid < 2 * EDIM) {
            inp_s[tid - EDIM] = xreg;
        }
        __syncthreads();                        // (5) inp ready

        // ---- LayerNorm over 2E=512, single pass (sum + sumsq), redundant finalize ----
        {
            float val = (tid < 2 * EDIM) ? inp_s[tid] : 0.f;
            float s1 = val, s2 = val * val;
#pragma unroll
            for (int mk = 32; mk > 0; mk >>= 1) {
                s1 += __shfl_xor(s1, mk, 64);
                s2 += __shfl_xor(s2, mk, 64);
            }
            if (lane == 0) { scr2[wv] = s1; scr2[NWAVES + wv] = s2; }
            __syncthreads();                    // (6) partials ready
            float S1 = 0.f, S2 = 0.f;
#pragma unroll
            for (int w = 0; w < NWAVES; ++w) { S1 += scr2[w]; S2 += scr2[NWAVES + w]; }
            float mu  = S1 * (1.0f / (2 * EDIM));
            float var = S2 * (1.0f / (2 * EDIM)) - mu * mu;
            float rs  = rsqrtf(var + 1e-5f);
            if (tid < 2 * EDIM) inpn_s[tid] = (val - mu) * rs * lng[tid] + lnb[tid];
        }
        __syncthreads();                        // (7) inpn ready

        // ---- Phase GX: gx = wih @ inpn (768x512). 1536 workers @ 64 iters,
        //      8-way k-split; worker owns 4 rows (float4, 1KB/wave coalesced).
        {
            auto gx_worker = [&](int w) {
                int q  = w / 192;               // k-chunk 0..7 (boundaries wave-aligned)
                int r4 = (w - q * 192) * 4;     // 0..764
                const float* base = wihT + (size_t)(q * 64) * 768 + r4;
                const float* xk = &inpn_s[q * 64];
                float a0 = 0.f, a1 = 0.f, a2 = 0.f, a3 = 0.f;
#pragma unroll 8
                for (int k = 0; k < 64; ++k) {
                    float4 w4 = *reinterpret_cast<const float4*>(base + (size_t)k * 768);
                    float x = xk[k];
                    a0 += w4.x * x; a1 += w4.y * x; a2 += w4.z * x; a3 += w4.w * x;
                }
                float4 acc; acc.x = a0; acc.y = a1; acc.z = a2; acc.w = a3;
                *reinterpret_cast<float4*>(&gxp[q * 768 + r4]) = acc;
            };
            gx_worker(tid);
            if (tid < 512) gx_worker(tid + 1024);
        }
        __syncthreads();                        // (8) gxp ready (vghp still holds gh)

        // ---- Phase E: gates, h update, output (torch gate order r,z,n) ----
        if (tid < EDIM) {
            const int j = tid;
            float xr = bih[j], xz = bih[EDIM + j], xn = bih[2 * EDIM + j];
#pragma unroll
            for (int q = 0; q < 8; ++q) {
                xr += gxp[q * 768 + j];
                xz += gxp[q * 768 + EDIM + j];
                xn += gxp[q * 768 + 2 * EDIM + j];
            }
            float hr = bhh[j], hz = bhh[EDIM + j], hn_ = bhh[2 * EDIM + j];
#pragma unroll
            for (int q = 0; q < 4; ++q) {
                hr  += vghp[q * 1024 + 256 + j];
                hz  += vghp[q * 1024 + 512 + j];
                hn_ += vghp[q * 1024 + 768 + j];
            }
            float r = 1.0f / (1.0f + __expf(-(xr + hr)));
            float z = 1.0f / (1.0f + __expf(-(xz + hz)));
            float n = tanhf(xn + r * hn_);
            float hnew = (1.0f - z) * n + z * h_s[j];
            h_s[j] = hnew;
            out[((size_t)b * SLEN + s) * EDIM + j] = hnew;
        }
        __syncthreads();                        // (9) h ready for next step
    }
}

extern "C" void kernel_launch(void* const* d_in, const int* in_sizes, int n_in,
                              void* d_out, int out_size, void* d_ws, size_t ws_size,
                              hipStream_t stream) {
    const float* signal = (const float*)d_in[0];
    const float* bases  = (const float*)d_in[1];
    const int*   mask   = (const int*)d_in[2];
    const float* Ww     = (const float*)d_in[3];
    const float* Wb     = (const float*)d_in[4];
    const float* lng    = (const float*)d_in[5];
    const float* lnb    = (const float*)d_in[6];
    const float* wih    = (const float*)d_in[7];
    const float* bih    = (const float*)d_in[8];
    const float* whh    = (const float*)d_in[9];
    const float* bhh    = (const float*)d_in[10];
    const float* hinit  = (const float*)d_in[11];
    float*       out    = (float*)d_out;

    const int B = in_sizes[0] / (TLEN * EDIM);   // 128

    // workspace (fp32): WcombT[256][1024] | wihT[512][768]   (~2.6 MB; sigT eliminated)
    float* WcombT = (float*)d_ws;
    float* wihT   = WcombT + 256 * 1024;

    // WcombT[k][j]   = Ww[j][k]        (j <  256)
    // WcombT[k][256+j] = whh[j][k]     (j <  768)
    transpose_pack_kernel<<<dim3(4, 4, 1),  256, 0, stream>>>(Ww,  WcombT, 256, 256, 1024, 0);
    transpose_pack_kernel<<<dim3(4, 12, 1), 256, 0, stream>>>(whh, WcombT, 768, 256, 1024, 256);
    // wihT[k][j] = wih[j][k]
    transpose_pack_kernel<<<dim3(8, 12, 1), 256, 0, stream>>>(wih, wihT, 768, 512, 768, 0);

    gru_decoder_kernel<<<dim3(B), dim3(NT), 0, stream>>>(
        signal, bases, mask, WcombT, Wb, lng, lnb, wihT, bih, bhh, hinit, out);
}